// Round 1
// baseline (145.437 us; speedup 1.0000x reference)
//
#include <hip/hip_runtime.h>
#include <hip/hip_bf16.h>

// MiniEq2Net round 9. B=8, n=256, nin=16, C=32, DH=128.  TWO launches.
//
//   h1[c,i,j] = relu( Q[c,i,j] + R1[c,i] + T1[c] + (i==j)*Dg1[c,i] )
//     Q = p[pos x 16d] . A1w[16d x 32c],  p_d = x[i,d]*x[j,d]  (symmetric)
//   out2(i,j)[s] = sum_c hA[c]W0[c,s] + hB[c]W1[c,s] + bcast  (u/v trick)
//   g[b,s] = sum_ij relu(out2); MLP 32->128->128->1.
//
// Round-9 changes vs round 8 (111.2 us, passing):
//  - W-transform tables (BQ, Wp/Wm K-permuted, W2-col4) precomputed ONCE by
//    kC block (0,0) into workspace; kD preamble becomes coalesced float4
//    copies instead of ~14 scattered VMEM + transform VALU per block x1088.
//  - kC stages W1 in LDS (float4) -> R1/Dg1/T1 section reads contiguous
//    LDS instead of ~128 scattered global loads per thread.
//  - k5 fused into kD: deterministic last-block-per-b tail (release fence +
//    atomic counter, acquire fence + agent-scope GP loads in the last
//    block). Same summation order as old k5 -> bit-identical output.
//    Counters zeroed by kC each launch (workspace is poisoned).

#define NB 8
#define NN 256
#define ND 16
#define NC 32
#define W1S 160   // W1 row stride (floats)
#define W2S 160   // W2 row stride (floats)
#define XP 20     // padded x row pitch (floats), 16B-aligned rows
#define NBLK 136  // kD blocks per batch

using bf16x8 = __attribute__((ext_vector_type(8))) __bf16;
using f32x4  = __attribute__((ext_vector_type(4))) float;

#define MFMA(a, b, c) __builtin_amdgcn_mfma_f32_16x16x32_bf16((a), (b), (c), 0, 0, 0)

// wave-local producer->consumer LDS sync
#define WAVE_LDS_SYNC() do {                      \
    __builtin_amdgcn_wave_barrier();              \
    __builtin_amdgcn_s_waitcnt(0xc07f); /* lgkmcnt(0) */ \
    __builtin_amdgcn_wave_barrier();              \
} while (0)

// Layer-1 A-fragment: av[j'] = xi[q*8+j'] * xj[q*8+j'] for quad<2, else 0.
__device__ __forceinline__ bf16x8 make_av(const float* xi, const float* xj, int quad)
{
    bf16x8 av;
    if (quad < 2) {
        const float4* a = (const float4*)(xi + quad * 8);
        const float4* b = (const float4*)(xj + quad * 8);
        float4 a0 = a[0], a1 = a[1], b0 = b[0], b1 = b[1];
        av[0] = (__bf16)(a0.x * b0.x); av[1] = (__bf16)(a0.y * b0.y);
        av[2] = (__bf16)(a0.z * b0.z); av[3] = (__bf16)(a0.w * b0.w);
        av[4] = (__bf16)(a1.x * b1.x); av[5] = (__bf16)(a1.y * b1.y);
        av[6] = (__bf16)(a1.z * b1.z); av[7] = (__bf16)(a1.w * b1.w);
    } else {
        #pragma unroll
        for (int j = 0; j < 8; ++j) av[j] = (__bf16)0.f;
    }
    return av;
}

__device__ __forceinline__ unsigned pack2(float lo, float hi)
{
    union { __bf16 b[2]; unsigned u; } p;
    p.b[0] = (__bf16)lo; p.b[1] = (__bf16)hi;
    return p.u;
}

// ---------------- kC: 4-row tiles; layer-1 row/diag/total sums + CD2/CR2 ----
// grid (64, NB), 256 threads. Each wave owns row i_l = wv.
// Block (0,0) additionally writes the shared W-tables + zeroes counters.
__global__ __launch_bounds__(256) void kC_rows(
    const float* __restrict__ x, const float* __restrict__ W1,
    const float* __restrict__ b1, const float* __restrict__ W2,
    float* __restrict__ T1g, float* __restrict__ R1, float* __restrict__ Dg1,
    float* __restrict__ TotP, float* __restrict__ CD2, float* __restrict__ CR2,
    __bf16* __restrict__ BQt, __bf16* __restrict__ Wpm,
    float* __restrict__ Wt4, int* __restrict__ Cnt)
{
    const int TI = blockIdx.x, b = blockIdx.y, t = threadIdx.x;
    __shared__ __align__(16) float  sX[NN][XP];       // 20 KB
    __shared__ __align__(16) float  sW1[2 * ND][W1S]; // 20 KB
    __shared__ __align__(16) __bf16 sBQ[NC][48];      // 3 KB
    __shared__ float part[16][ND + 1];
    __shared__ float sS[ND];
    __shared__ float sRT[4][NC], sDgL[4][NC], sRow[4][NC], sDiag[4][NC];

    {   // float4 x staging: 1024 float4s, 4 per thread
        const float4* xg4 = (const float4*)(x + b * NN * ND);
        #pragma unroll
        for (int kk = 0; kk < 4; ++kk) {
            int idx = t + kk * 256;              // float4 index
            int row = idx >> 2, c4 = idx & 3;
            *(float4*)&sX[row][c4 * 4] = xg4[idx];
        }
    }
    {   // float4 W1 staging: 1280 float4s, 5 per thread
        const float4* wg1 = (const float4*)W1;
        float4* sw1 = (float4*)&sW1[0][0];
        #pragma unroll
        for (int kk = 0; kk < 5; ++kk) sw1[t + kk * 256] = wg1[t + kk * 256];
    }
    #pragma unroll
    for (int kk = 0; kk < 2; ++kk) {   // A1w B-table (k<16), rest zero
        int idx = t + kk * 256; int c = idx >> 4, k = idx & 15;
        sBQ[c][k] = (__bf16)(W1[(ND + k) * W1S + c * 5 + 0]
                           + W1[(ND + k) * W1S + c * 5 + 1]);
    }
    #pragma unroll
    for (int kk = 0; kk < 4; ++kk) {
        int idx = t + kk * 256;
        sBQ[idx >> 5][16 + (idx & 31)] = (__bf16)0.f;
    }
    __syncthreads();

    {   // column sums S[d]
        int rr = t >> 4, d = t & 15;
        float p = 0.f;
        #pragma unroll
        for (int k = 0; k < 16; ++k) p += sX[rr + (k << 4)][d];
        part[rr][d] = p;
    }
    if (TI == 0 && b == 0) {   // shared tables (values identical to what kD
                               // round-8 computed per-block) + counters
        if (t < 192) ((float4*)BQt)[t] = ((const float4*)&sBQ[0][0])[t];
        for (int idx = t; idx < 1024; idx += 256) {
            int s = idx >> 5, kp = idx & 31;
            int c = ((kp & 1) << 4) | (kp >> 1);
            float w0 = W2[c * W2S + s * 5 + 0], w1 = W2[c * W2S + s * 5 + 1];
            Wpm[s * 40 + kp]        = (__bf16)((w0 + w1) * 0.5f);
            Wpm[1280 + s * 40 + kp] = (__bf16)((w0 - w1) * 0.5f);
        }
        for (int idx = t; idx < 1024; idx += 256)
            Wt4[(idx >> 5) * 32 + (idx & 31)] = W2[(idx >> 5) * W2S + (idx & 31) * 5 + 4];
        if (t < NB) Cnt[t] = 0;
    }
    __syncthreads();
    if (t < ND) {
        float s = 0.f;
        #pragma unroll
        for (int k = 0; k < 16; ++k) s += part[k][t];
        sS[t] = s;
    }
    __syncthreads();
    if (t < 128) {   // R1/Dg1/T1 fused for the 4 tile rows (W1 from LDS)
        int i_l = t >> 5, c = t & 31;
        int gi = TI * 4 + i_l;
        float r = 0.f, dg = 0.f, tt = 0.f;
        #pragma unroll
        for (int d = 0; d < ND; ++d) {
            float xi = sX[gi][d], sd = sS[d];
            const float* wa = &sW1[d][c * 5];
            const float* wb = &sW1[ND + d][c * 5];
            r  += xi * wa[3] + xi * sd * wb[3];
            dg += xi * (wa[0] + wa[1] + wa[2]) + xi * xi * wb[2];
            tt += sd * wa[4] + sd * sd * wb[4];
        }
        r *= (1.f / 256.f);
        float t1 = tt * (1.f / 65536.f) + b1[c];
        R1[(b * NN + gi) * NC + c] = r;
        Dg1[(b * NN + gi) * NC + c] = dg;
        sRT[i_l][c] = t1 + r;
        sDgL[i_l][c] = dg;
        if (TI == 0 && i_l == 0) T1g[b * NC + c] = t1;
    }
    __syncthreads();

    const int ln = t & 63, wv = t >> 6;
    const int m = ln & 15, quad = ln >> 4;
    const int gi = TI * 4 + wv;          // this wave's row
    bf16x8 bq0 = *(const bf16x8*)&sBQ[m][8 * quad];
    bf16x8 bq1 = *(const bf16x8*)&sBQ[m + 16][8 * quad];
    float rt0 = sRT[wv][m], rt1 = sRT[wv][m + 16];
    float dg0 = sDgL[wv][m], dg1 = sDgL[wv][m + 16];
    f32x4 zero = {0.f, 0.f, 0.f, 0.f};
    float rs0 = 0.f, rs1 = 0.f;

    // barrier-free strip loop: A-fragments in-register from sX
    for (int jg = 0; jg < 8; ++jg) {
        #pragma unroll
        for (int gg = 0; gg < 2; ++gg) {
            int jrow = jg * 32 + gg * 16 + m;
            bf16x8 av = make_av(&sX[gi][0], &sX[jrow][0], quad);
            f32x4 q0 = MFMA(av, bq0, zero);
            f32x4 q1 = MFMA(av, bq1, zero);
            int jb = jg * 32 + gg * 16 + quad * 4;
            #pragma unroll
            for (int r = 0; r < 4; ++r) {
                float v0 = q0[r] + rt0, v1 = q1[r] + rt1;
                bool dgf = (jb + r == gi);
                if (dgf) { v0 += dg0; v1 += dg1; }
                float h0 = fmaxf(v0, 0.f), h1 = fmaxf(v1, 0.f);
                if (dgf) { sDiag[wv][m] = h0; sDiag[wv][m + 16] = h1; }
                rs0 += h0; rs1 += h1;
            }
        }
    }
    rs0 += __shfl_down(rs0, 32, 64); rs0 += __shfl_down(rs0, 16, 64);
    rs1 += __shfl_down(rs1, 32, 64); rs1 += __shfl_down(rs1, 16, 64);
    if (ln < 16) { sRow[wv][ln] = rs0; sRow[wv][ln + 16] = rs1; }
    __syncthreads();
    if (t < NC)
        TotP[TI * (NB * NC) + b * NC + t]
            = sRow[0][t] + sRow[1][t] + sRow[2][t] + sRow[3][t];
    if (t < 128) {   // CD2/CR2 for the 4 rows (raw W2, L2-hot)
        int i_l = t >> 5, s = t & 31;
        int gi2 = TI * 4 + i_l;
        float cd = 0.f, cr = 0.f;
        #pragma unroll
        for (int c = 0; c < NC; ++c) {
            cd += sDiag[i_l][c] * W2[c * W2S + s * 5 + 2];
            cr += sRow[i_l][c]  * W2[c * W2S + s * 5 + 3];
        }
        CD2[(b * NN + gi2) * NC + s] = cd;
        CR2[(b * NN + gi2) * NC + s] = cr * (1.f / 256.f);
    }
}

// ---------------- kD: tile-pair layer1+layer2+reduce; per-wave U/V ----------
// grid (136, NB), 256 threads. Single preamble barrier.
// Last block per b (atomic counter) runs the old-k5 reduction + MLP tail.
__global__ __launch_bounds__(256) void kD_main(
    const float* __restrict__ x,
    const __bf16* __restrict__ BQt, const __bf16* __restrict__ Wpm,
    const float* __restrict__ Wt4, const float* __restrict__ b2,
    const float* __restrict__ T1g, const float* __restrict__ R1g,
    const float* __restrict__ Dg1g, const float* __restrict__ CD2g,
    const float* __restrict__ CR2g, const float* __restrict__ TotP,
    float* __restrict__ GP, int* __restrict__ Cnt,
    const float* __restrict__ D1, const float* __restrict__ db1,
    const float* __restrict__ D2, const float* __restrict__ db2,
    const float* __restrict__ D3, const float* __restrict__ db3,
    float* __restrict__ out)
{
    const int b = blockIdx.y, t = threadIdx.x;
    int TI = 0, rem = blockIdx.x;
    while (rem >= 16 - TI) { rem -= 16 - TI; ++TI; }
    const int TJ = TI + rem;
    const bool diagblk = (TI == TJ), mirror = !diagblk;

    __shared__ __align__(16) __bf16 sUw[4][16][40];   // per-wave U
    __shared__ __align__(16) __bf16 sVw[4][16][40];   // per-wave V
    __shared__ __align__(16) __bf16 sBQ[NC][48];
    __shared__ __align__(16) __bf16 sWp[NC][40], sWm[NC][40];  // K-permuted
    __shared__ __align__(16) float sXI[16][XP], sXJ[16][XP];
    __shared__ float sTot[NC], sCT2[NC];
    __shared__ float red[4][NC];
    __shared__ int sLast;
    __shared__ float sGp[8][NC], sA[NC], h2s[128], r2[2];

    if (t < 128) {   // float4 x staging: 64 float4s per tile
        const float4* xg4 = (const float4*)(x + b * NN * ND);
        int half = t >> 6, idx = t & 63;      // half 0 -> XI, 1 -> XJ
        int row = idx >> 2, c4 = idx & 3;
        int base = (half ? TJ : TI) * 16;
        float4 v = xg4[(base + row) * 4 + c4];
        float* dst = half ? &sXJ[row][c4 * 4] : &sXI[row][c4 * 4];
        *(float4*)dst = v;
    }
    // coalesced table copies (values identical to round-8 per-block compute)
    if (t < 192) ((float4*)&sBQ[0][0])[t] = ((const float4*)BQt)[t];
    {
        const float4* wsrc = (const float4*)Wpm;   // 160 f4 Wp, then 160 f4 Wm
        #pragma unroll
        for (int i = t; i < 320; i += 256) {
            float4 v = wsrc[i];
            if (i < 160) ((float4*)&sWp[0][0])[i] = v;
            else         ((float4*)&sWm[0][0])[i - 160] = v;
        }
    }
    if (t < NC) {   // wave 0: TotP reduce -> sTot
        float tot = 0.f;
        #pragma unroll
        for (int k = 0; k < 64; ++k) tot += TotP[k * (NB * NC) + b * NC + t];
        sTot[t] = tot;
    }
    if (t < 64) {   // wave-local handoff: sTot (wave 0) -> sCT2 (wave 0)
        WAVE_LDS_SYNC();
        if (t < NC) {
            float ct = 0.f;
            #pragma unroll
            for (int c = 0; c < NC; ++c) ct += sTot[c] * Wt4[c * 32 + t];
            sCT2[t] = ct * (1.f / 65536.f) + b2[t];
        }
    }

    const int ln = t & 63, wv = t >> 6;
    const int m = ln & 15, quad = ln >> 4;

    // epilogue constants -> registers (issued pre-barrier, L2-hot, coalesced)
    const float* R1b = R1g + b * NN * NC;
    const float* Dgb = Dg1g + b * NN * NC;
    const float* CDb = CD2g + b * NN * NC;
    const float* CRb = CR2g + b * NN * NC;
    float t10 = T1g[b * NC + m], t11 = T1g[b * NC + m + 16];
    float rti[4][2], dgi[4][2], rtj[4][2];
    float cri[4][2], cdi[4][2], crj[4][2];
    #pragma unroll
    for (int gg = 0; gg < 4; ++gg) {
        int rowI = TI * 16 + wv * 4 + gg;
        rti[gg][0] = R1b[rowI * NC + m] + t10;
        rti[gg][1] = R1b[rowI * NC + m + 16] + t11;
        dgi[gg][0] = Dgb[rowI * NC + m];
        dgi[gg][1] = Dgb[rowI * NC + m + 16];
        cri[gg][0] = CRb[rowI * NC + m];
        cri[gg][1] = CRb[rowI * NC + m + 16];
        cdi[gg][0] = CDb[rowI * NC + m];
        cdi[gg][1] = CDb[rowI * NC + m + 16];
    }
    #pragma unroll
    for (int r = 0; r < 4; ++r) {
        int rowJ = TJ * 16 + quad * 4 + r;
        rtj[r][0] = R1b[rowJ * NC + m] + t10;
        rtj[r][1] = R1b[rowJ * NC + m + 16] + t11;
        crj[r][0] = CRb[rowJ * NC + m];
        crj[r][1] = CRb[rowJ * NC + m + 16];
    }
    __syncthreads();   // single preamble barrier

    float ct0 = sCT2[m], ct1 = sCT2[m + 16];
    #pragma unroll
    for (int gg = 0; gg < 4; ++gg) { cri[gg][0] += ct0; cri[gg][1] += ct1; }
    #pragma unroll
    for (int r = 0; r < 4; ++r) { crj[r][0] += ct0; crj[r][1] += ct1; }

    bf16x8 bq0 = *(const bf16x8*)&sBQ[m][8 * quad];
    bf16x8 bq1 = *(const bf16x8*)&sBQ[m + 16][8 * quad];
    bf16x8 wp0 = *(const bf16x8*)&sWp[m][8 * quad];
    bf16x8 wp1 = *(const bf16x8*)&sWp[m + 16][8 * quad];
    bf16x8 wm0 = *(const bf16x8*)&sWm[m][8 * quad];
    bf16x8 wm1 = *(const bf16x8*)&sWm[m + 16][8 * quad];
    __bf16* Uw = &sUw[wv][0][0];
    __bf16* Vw = &sVw[wv][0][0];
    f32x4 zero = {0.f, 0.f, 0.f, 0.f};
    float acc0 = 0.f, acc1 = 0.f;

    // barrier-free main loop: per-wave U/V with wave-local LDS handoff
    #pragma unroll
    for (int gg = 0; gg < 4; ++gg) {
        int g = wv * 4 + gg;
        __builtin_amdgcn_wave_barrier();   // keep prior gg's reads before writes
        {   // layer-1: h = relu(Q + T1 + R1 [+Dg]); write packed U/V
            bf16x8 av = make_av(&sXI[g][0], &sXJ[m][0], quad);
            f32x4 q0 = MFMA(av, bq0, zero);
            f32x4 q1 = MFMA(av, bq1, zero);
            #pragma unroll
            for (int r = 0; r < 4; ++r) {
                int tj = quad * 4 + r;
                float a0 = q0[r] + rti[gg][0], b0 = q0[r] + rtj[r][0];
                float a1 = q1[r] + rti[gg][1], b1 = q1[r] + rtj[r][1];
                if (diagblk && tj == g) {
                    a0 += dgi[gg][0]; b0 = a0;
                    a1 += dgi[gg][1]; b1 = a1;
                }
                float hA0 = fmaxf(a0, 0.f), hB0 = fmaxf(b0, 0.f);
                float hA1 = fmaxf(a1, 0.f), hB1 = fmaxf(b1, 0.f);
                *(unsigned*)&Uw[tj * 40 + 2 * m] = pack2(hA0 + hB0, hA1 + hB1);
                *(unsigned*)&Vw[tj * 40 + 2 * m] = pack2(hA0 - hB0, hA1 - hB1);
            }
        }
        WAVE_LDS_SYNC();
        {   // layer-2: a1 = U.Wp + V.Wm + bcast_i, a2 = U.Wp - V.Wm + bcast_j
            bf16x8 ua = *(const bf16x8*)&Uw[m * 40 + 8 * quad];
            bf16x8 va = *(const bf16x8*)&Vw[m * 40 + 8 * quad];
            f32x4 P0 = MFMA(ua, wp0, zero);
            f32x4 M0 = MFMA(va, wm0, zero);
            f32x4 P1 = MFMA(ua, wp1, zero);
            f32x4 M1 = MFMA(va, wm1, zero);
            #pragma unroll
            for (int r = 0; r < 4; ++r) {
                int tj = quad * 4 + r;
                float a1v = P0[r] + M0[r] + cri[gg][0];
                float a2v = P0[r] - M0[r] + crj[r][0];
                float e1 = P1[r] + M1[r] + cri[gg][1];
                float e2 = P1[r] - M1[r] + crj[r][1];
                if (diagblk && tj == g) { a1v += cdi[gg][0]; e1 += cdi[gg][1]; }
                acc0 += fmaxf(a1v, 0.f); acc1 += fmaxf(e1, 0.f);
                if (mirror) { acc0 += fmaxf(a2v, 0.f); acc1 += fmaxf(e2, 0.f); }
            }
        }
    }

    acc0 += __shfl_down(acc0, 32, 64); acc0 += __shfl_down(acc0, 16, 64);
    acc1 += __shfl_down(acc1, 32, 64); acc1 += __shfl_down(acc1, 16, 64);
    if (ln < 16) { red[wv][ln] = acc0; red[wv][ln + 16] = acc1; }
    __syncthreads();
    if (t < NC)
        GP[blockIdx.x * (NB * NC) + b * NC + t]
            = red[0][t] + red[1][t] + red[2][t] + red[3][t];

    // ---- last-block-per-b tail: old k5 (bit-identical order) ----
    __builtin_amdgcn_fence(__ATOMIC_RELEASE, "agent");   // flush GP to coherent point
    if (t == 0) {
        int old = __hip_atomic_fetch_add(Cnt + b, 1, __ATOMIC_RELAXED,
                                         __HIP_MEMORY_SCOPE_AGENT);
        sLast = (old == NBLK - 1) ? 1 : 0;
    }
    __syncthreads();
    if (!sLast) return;
    __builtin_amdgcn_fence(__ATOMIC_ACQUIRE, "agent");   // only 8 blocks pay this

    {
        int q = t >> 5, s = t & 31;
        float p = 0.f;
        #pragma unroll
        for (int k = q; k < NBLK; k += 8)
            p += __hip_atomic_load(&GP[k * (NB * NC) + b * NC + s],
                                   __ATOMIC_RELAXED, __HIP_MEMORY_SCOPE_AGENT);
        sGp[q][s] = p;
    }
    __syncthreads();
    if (t < NC) {
        float s = 0.f;
        #pragma unroll
        for (int q = 0; q < 8; ++q) s += sGp[q][t];
        sA[t] = fmaxf(s, 0.f);
    }
    __syncthreads();
    if (t < 128) {
        float acc = db1[t];
        #pragma unroll
        for (int s = 0; s < NC; ++s) acc += sA[s] * D1[s * 128 + t];
        h2s[t] = fmaxf(acc, 0.f);
    }
    __syncthreads();
    if (t < 128) {
        float acc2 = db2[t];
        #pragma unroll 8
        for (int u = 0; u < 128; ++u) acc2 += h2s[u] * D2[u * 128 + t];
        float h3 = fmaxf(acc2, 0.f);
        float v = h3 * D3[t];
        #pragma unroll
        for (int off = 32; off > 0; off >>= 1) v += __shfl_down(v, off, 64);
        if ((t & 63) == 0) r2[t >> 6] = v;
    }
    __syncthreads();
    if (t == 0) out[b] = r2[0] + r2[1] + db3[0];
}

extern "C" void kernel_launch(void* const* d_in, const int* in_sizes, int n_in,
                              void* d_out, int out_size, void* d_ws, size_t ws_size,
                              hipStream_t stream)
{
    const float* x   = (const float*)d_in[0];
    const float* W1  = (const float*)d_in[1];
    const float* b1  = (const float*)d_in[2];
    const float* W2  = (const float*)d_in[3];
    const float* b2  = (const float*)d_in[4];
    const float* D1  = (const float*)d_in[5];
    const float* db1 = (const float*)d_in[6];
    const float* D2  = (const float*)d_in[7];
    const float* db2 = (const float*)d_in[8];
    const float* D3  = (const float*)d_in[9];
    const float* db3 = (const float*)d_in[10];
    float* out = (float*)d_out;

    float* w = (float*)d_ws;
    float* pT1   = w; w += NB * NC;          // 256
    float* pTotP = w; w += 64 * NB * NC;     // 16384
    float* pGP   = w; w += NBLK * NB * NC;   // 34816
    float* pR1   = w; w += NB * NN * NC;     // 65536
    float* pDg1  = w; w += NB * NN * NC;
    float* pCD2  = w; w += NB * NN * NC;
    float* pCR2  = w; w += NB * NN * NC;
    __bf16* pBQt = (__bf16*)w; w += 768;     // 1536 bf16 = 32x48
    __bf16* pWpm = (__bf16*)w; w += 1280;    // 2560 bf16 = Wp[32x40] + Wm[32x40]
    float* pWt4  = w; w += 1024;             // f32 [c][s]
    int*   pCnt  = (int*)w; w += 8;

    hipLaunchKernelGGL(kC_rows, dim3(64, NB), dim3(256), 0, stream,
                       x, W1, b1, W2, pT1, pR1, pDg1, pTotP, pCD2, pCR2,
                       pBQt, pWpm, pWt4, pCnt);
    hipLaunchKernelGGL(kD_main, dim3(NBLK, NB), dim3(256), 0, stream,
                       x, pBQt, pWpm, pWt4, b2, pT1, pR1, pDg1, pCD2, pCR2,
                       pTotP, pGP, pCnt, D1, db1, D2, db2, D3, db3, out);
}

// Round 2
// 109.960 us; speedup vs baseline: 1.3226x; 1.3226x over previous
//
#include <hip/hip_runtime.h>
#include <hip/hip_bf16.h>

// MiniEq2Net round 10. B=8, n=256, nin=16, C=32, DH=128.  Three launches.
//
//   h1[c,i,j] = relu( Q[c,i,j] + R1[c,i] + T1[c] + (i==j)*Dg1[c,i] )
//     Q = p[pos x 16d] . A1w[16d x 32c],  p_d = x[i,d]*x[j,d]  (symmetric)
//   out2(i,j)[s] = sum_c hA[c]W0[c,s] + hB[c]W1[c,s] + bcast  (u/v trick)
//   g[b,s] = sum_ij relu(out2); MLP 32->128->128->1.
//
// Round-10 changes vs round 9 (145.4 us, REGRESSION):
//  - REVERTED the k5-into-kD fusion. The per-block agent-scope release
//    fence lowers to buffer_wbl2 (full L2 writeback) on gfx950; 1088
//    blocks doing that cost +30 us on kD (rocprof: kD 66 us, all pipes
//    idle). Back to the separate k5 launch (round-8 structure).
//  - KEPT from round 9: W-transform tables (BQ, Wp/Wm, W2-col4)
//    precomputed once by kC block (0,0); kD preamble is coalesced float4
//    copies. kC stages W1 in LDS (float4) for the R1/Dg1/T1 section.

#define NB 8
#define NN 256
#define ND 16
#define NC 32
#define W1S 160   // W1 row stride (floats)
#define W2S 160   // W2 row stride (floats)
#define XP 20     // padded x row pitch (floats), 16B-aligned rows
#define NBLK 136  // kD blocks per batch

using bf16x8 = __attribute__((ext_vector_type(8))) __bf16;
using f32x4  = __attribute__((ext_vector_type(4))) float;

#define MFMA(a, b, c) __builtin_amdgcn_mfma_f32_16x16x32_bf16((a), (b), (c), 0, 0, 0)

// wave-local producer->consumer LDS sync
#define WAVE_LDS_SYNC() do {                      \
    __builtin_amdgcn_wave_barrier();              \
    __builtin_amdgcn_s_waitcnt(0xc07f); /* lgkmcnt(0) */ \
    __builtin_amdgcn_wave_barrier();              \
} while (0)

// Layer-1 A-fragment: av[j'] = xi[q*8+j'] * xj[q*8+j'] for quad<2, else 0.
__device__ __forceinline__ bf16x8 make_av(const float* xi, const float* xj, int quad)
{
    bf16x8 av;
    if (quad < 2) {
        const float4* a = (const float4*)(xi + quad * 8);
        const float4* b = (const float4*)(xj + quad * 8);
        float4 a0 = a[0], a1 = a[1], b0 = b[0], b1 = b[1];
        av[0] = (__bf16)(a0.x * b0.x); av[1] = (__bf16)(a0.y * b0.y);
        av[2] = (__bf16)(a0.z * b0.z); av[3] = (__bf16)(a0.w * b0.w);
        av[4] = (__bf16)(a1.x * b1.x); av[5] = (__bf16)(a1.y * b1.y);
        av[6] = (__bf16)(a1.z * b1.z); av[7] = (__bf16)(a1.w * b1.w);
    } else {
        #pragma unroll
        for (int j = 0; j < 8; ++j) av[j] = (__bf16)0.f;
    }
    return av;
}

__device__ __forceinline__ unsigned pack2(float lo, float hi)
{
    union { __bf16 b[2]; unsigned u; } p;
    p.b[0] = (__bf16)lo; p.b[1] = (__bf16)hi;
    return p.u;
}

// ---------------- kC: 4-row tiles; layer-1 row/diag/total sums + CD2/CR2 ----
// grid (64, NB), 256 threads. Each wave owns row i_l = wv.
// Block (0,0) additionally writes the shared W-tables.
__global__ __launch_bounds__(256) void kC_rows(
    const float* __restrict__ x, const float* __restrict__ W1,
    const float* __restrict__ b1, const float* __restrict__ W2,
    float* __restrict__ T1g, float* __restrict__ R1, float* __restrict__ Dg1,
    float* __restrict__ TotP, float* __restrict__ CD2, float* __restrict__ CR2,
    __bf16* __restrict__ BQt, __bf16* __restrict__ Wpm,
    float* __restrict__ Wt4)
{
    const int TI = blockIdx.x, b = blockIdx.y, t = threadIdx.x;
    __shared__ __align__(16) float  sX[NN][XP];       // 20 KB
    __shared__ __align__(16) float  sW1[2 * ND][W1S]; // 20 KB
    __shared__ __align__(16) __bf16 sBQ[NC][48];      // 3 KB
    __shared__ float part[16][ND + 1];
    __shared__ float sS[ND];
    __shared__ float sRT[4][NC], sDgL[4][NC], sRow[4][NC], sDiag[4][NC];

    {   // float4 x staging: 1024 float4s, 4 per thread
        const float4* xg4 = (const float4*)(x + b * NN * ND);
        #pragma unroll
        for (int kk = 0; kk < 4; ++kk) {
            int idx = t + kk * 256;              // float4 index
            int row = idx >> 2, c4 = idx & 3;
            *(float4*)&sX[row][c4 * 4] = xg4[idx];
        }
    }
    {   // float4 W1 staging: 1280 float4s, 5 per thread
        const float4* wg1 = (const float4*)W1;
        float4* sw1 = (float4*)&sW1[0][0];
        #pragma unroll
        for (int kk = 0; kk < 5; ++kk) sw1[t + kk * 256] = wg1[t + kk * 256];
    }
    #pragma unroll
    for (int kk = 0; kk < 2; ++kk) {   // A1w B-table (k<16), rest zero
        int idx = t + kk * 256; int c = idx >> 4, k = idx & 15;
        sBQ[c][k] = (__bf16)(W1[(ND + k) * W1S + c * 5 + 0]
                           + W1[(ND + k) * W1S + c * 5 + 1]);
    }
    #pragma unroll
    for (int kk = 0; kk < 4; ++kk) {
        int idx = t + kk * 256;
        sBQ[idx >> 5][16 + (idx & 31)] = (__bf16)0.f;
    }
    __syncthreads();

    {   // column sums S[d]
        int rr = t >> 4, d = t & 15;
        float p = 0.f;
        #pragma unroll
        for (int k = 0; k < 16; ++k) p += sX[rr + (k << 4)][d];
        part[rr][d] = p;
    }
    if (TI == 0 && b == 0) {   // shared tables (values identical to what kD
                               // round-8 computed per-block)
        if (t < 192) ((float4*)BQt)[t] = ((const float4*)&sBQ[0][0])[t];
        for (int idx = t; idx < 1024; idx += 256) {
            int s = idx >> 5, kp = idx & 31;
            int c = ((kp & 1) << 4) | (kp >> 1);
            float w0 = W2[c * W2S + s * 5 + 0], w1 = W2[c * W2S + s * 5 + 1];
            Wpm[s * 40 + kp]        = (__bf16)((w0 + w1) * 0.5f);
            Wpm[1280 + s * 40 + kp] = (__bf16)((w0 - w1) * 0.5f);
        }
        for (int idx = t; idx < 1024; idx += 256)
            Wt4[(idx >> 5) * 32 + (idx & 31)] = W2[(idx >> 5) * W2S + (idx & 31) * 5 + 4];
    }
    __syncthreads();
    if (t < ND) {
        float s = 0.f;
        #pragma unroll
        for (int k = 0; k < 16; ++k) s += part[k][t];
        sS[t] = s;
    }
    __syncthreads();
    if (t < 128) {   // R1/Dg1/T1 fused for the 4 tile rows (W1 from LDS)
        int i_l = t >> 5, c = t & 31;
        int gi = TI * 4 + i_l;
        float r = 0.f, dg = 0.f, tt = 0.f;
        #pragma unroll
        for (int d = 0; d < ND; ++d) {
            float xi = sX[gi][d], sd = sS[d];
            const float* wa = &sW1[d][c * 5];
            const float* wb = &sW1[ND + d][c * 5];
            r  += xi * wa[3] + xi * sd * wb[3];
            dg += xi * (wa[0] + wa[1] + wa[2]) + xi * xi * wb[2];
            tt += sd * wa[4] + sd * sd * wb[4];
        }
        r *= (1.f / 256.f);
        float t1 = tt * (1.f / 65536.f) + b1[c];
        R1[(b * NN + gi) * NC + c] = r;
        Dg1[(b * NN + gi) * NC + c] = dg;
        sRT[i_l][c] = t1 + r;
        sDgL[i_l][c] = dg;
        if (TI == 0 && i_l == 0) T1g[b * NC + c] = t1;
    }
    __syncthreads();

    const int ln = t & 63, wv = t >> 6;
    const int m = ln & 15, quad = ln >> 4;
    const int gi = TI * 4 + wv;          // this wave's row
    bf16x8 bq0 = *(const bf16x8*)&sBQ[m][8 * quad];
    bf16x8 bq1 = *(const bf16x8*)&sBQ[m + 16][8 * quad];
    float rt0 = sRT[wv][m], rt1 = sRT[wv][m + 16];
    float dg0 = sDgL[wv][m], dg1 = sDgL[wv][m + 16];
    f32x4 zero = {0.f, 0.f, 0.f, 0.f};
    float rs0 = 0.f, rs1 = 0.f;

    // barrier-free strip loop: A-fragments in-register from sX
    for (int jg = 0; jg < 8; ++jg) {
        #pragma unroll
        for (int gg = 0; gg < 2; ++gg) {
            int jrow = jg * 32 + gg * 16 + m;
            bf16x8 av = make_av(&sX[gi][0], &sX[jrow][0], quad);
            f32x4 q0 = MFMA(av, bq0, zero);
            f32x4 q1 = MFMA(av, bq1, zero);
            int jb = jg * 32 + gg * 16 + quad * 4;
            #pragma unroll
            for (int r = 0; r < 4; ++r) {
                float v0 = q0[r] + rt0, v1 = q1[r] + rt1;
                bool dgf = (jb + r == gi);
                if (dgf) { v0 += dg0; v1 += dg1; }
                float h0 = fmaxf(v0, 0.f), h1 = fmaxf(v1, 0.f);
                if (dgf) { sDiag[wv][m] = h0; sDiag[wv][m + 16] = h1; }
                rs0 += h0; rs1 += h1;
            }
        }
    }
    rs0 += __shfl_down(rs0, 32, 64); rs0 += __shfl_down(rs0, 16, 64);
    rs1 += __shfl_down(rs1, 32, 64); rs1 += __shfl_down(rs1, 16, 64);
    if (ln < 16) { sRow[wv][ln] = rs0; sRow[wv][ln + 16] = rs1; }
    __syncthreads();
    if (t < NC)
        TotP[TI * (NB * NC) + b * NC + t]
            = sRow[0][t] + sRow[1][t] + sRow[2][t] + sRow[3][t];
    if (t < 128) {   // CD2/CR2 for the 4 rows (raw W2, L2-hot)
        int i_l = t >> 5, s = t & 31;
        int gi2 = TI * 4 + i_l;
        float cd = 0.f, cr = 0.f;
        #pragma unroll
        for (int c = 0; c < NC; ++c) {
            cd += sDiag[i_l][c] * W2[c * W2S + s * 5 + 2];
            cr += sRow[i_l][c]  * W2[c * W2S + s * 5 + 3];
        }
        CD2[(b * NN + gi2) * NC + s] = cd;
        CR2[(b * NN + gi2) * NC + s] = cr * (1.f / 256.f);
    }
}

// ---------------- kD: tile-pair layer1+layer2+reduce; per-wave U/V ----------
// grid (136, NB), 256 threads. Single preamble barrier.
__global__ __launch_bounds__(256) void kD_main(
    const float* __restrict__ x,
    const __bf16* __restrict__ BQt, const __bf16* __restrict__ Wpm,
    const float* __restrict__ Wt4, const float* __restrict__ b2,
    const float* __restrict__ T1g, const float* __restrict__ R1g,
    const float* __restrict__ Dg1g, const float* __restrict__ CD2g,
    const float* __restrict__ CR2g, const float* __restrict__ TotP,
    float* __restrict__ GP)
{
    const int b = blockIdx.y, t = threadIdx.x;
    int TI = 0, rem = blockIdx.x;
    while (rem >= 16 - TI) { rem -= 16 - TI; ++TI; }
    const int TJ = TI + rem;
    const bool diagblk = (TI == TJ), mirror = !diagblk;

    __shared__ __align__(16) __bf16 sUw[4][16][40];   // per-wave U
    __shared__ __align__(16) __bf16 sVw[4][16][40];   // per-wave V
    __shared__ __align__(16) __bf16 sBQ[NC][48];
    __shared__ __align__(16) __bf16 sWp[NC][40], sWm[NC][40];  // K-permuted
    __shared__ __align__(16) float sXI[16][XP], sXJ[16][XP];
    __shared__ float sTot[NC], sCT2[NC];
    __shared__ float red[4][NC];

    if (t < 128) {   // float4 x staging: 64 float4s per tile
        const float4* xg4 = (const float4*)(x + b * NN * ND);
        int half = t >> 6, idx = t & 63;      // half 0 -> XI, 1 -> XJ
        int row = idx >> 2, c4 = idx & 3;
        int base = (half ? TJ : TI) * 16;
        float4 v = xg4[(base + row) * 4 + c4];
        float* dst = half ? &sXJ[row][c4 * 4] : &sXI[row][c4 * 4];
        *(float4*)dst = v;
    }
    // coalesced table copies (values identical to round-8 per-block compute)
    if (t < 192) ((float4*)&sBQ[0][0])[t] = ((const float4*)BQt)[t];
    {
        const float4* wsrc = (const float4*)Wpm;   // 160 f4 Wp, then 160 f4 Wm
        #pragma unroll
        for (int i = t; i < 320; i += 256) {
            float4 v = wsrc[i];
            if (i < 160) ((float4*)&sWp[0][0])[i] = v;
            else         ((float4*)&sWm[0][0])[i - 160] = v;
        }
    }
    if (t < NC) {   // wave 0: TotP reduce -> sTot
        float tot = 0.f;
        #pragma unroll
        for (int k = 0; k < 64; ++k) tot += TotP[k * (NB * NC) + b * NC + t];
        sTot[t] = tot;
    }
    if (t < 64) {   // wave-local handoff: sTot (wave 0) -> sCT2 (wave 0)
        WAVE_LDS_SYNC();
        if (t < NC) {
            float ct = 0.f;
            #pragma unroll
            for (int c = 0; c < NC; ++c) ct += sTot[c] * Wt4[c * 32 + t];
            sCT2[t] = ct * (1.f / 65536.f) + b2[t];
        }
    }

    const int ln = t & 63, wv = t >> 6;
    const int m = ln & 15, quad = ln >> 4;

    // epilogue constants -> registers (issued pre-barrier, L2-hot, coalesced)
    const float* R1b = R1g + b * NN * NC;
    const float* Dgb = Dg1g + b * NN * NC;
    const float* CDb = CD2g + b * NN * NC;
    const float* CRb = CR2g + b * NN * NC;
    float t10 = T1g[b * NC + m], t11 = T1g[b * NC + m + 16];
    float rti[4][2], dgi[4][2], rtj[4][2];
    float cri[4][2], cdi[4][2], crj[4][2];
    #pragma unroll
    for (int gg = 0; gg < 4; ++gg) {
        int rowI = TI * 16 + wv * 4 + gg;
        rti[gg][0] = R1b[rowI * NC + m] + t10;
        rti[gg][1] = R1b[rowI * NC + m + 16] + t11;
        dgi[gg][0] = Dgb[rowI * NC + m];
        dgi[gg][1] = Dgb[rowI * NC + m + 16];
        cri[gg][0] = CRb[rowI * NC + m];
        cri[gg][1] = CRb[rowI * NC + m + 16];
        cdi[gg][0] = CDb[rowI * NC + m];
        cdi[gg][1] = CDb[rowI * NC + m + 16];
    }
    #pragma unroll
    for (int r = 0; r < 4; ++r) {
        int rowJ = TJ * 16 + quad * 4 + r;
        rtj[r][0] = R1b[rowJ * NC + m] + t10;
        rtj[r][1] = R1b[rowJ * NC + m + 16] + t11;
        crj[r][0] = CRb[rowJ * NC + m];
        crj[r][1] = CRb[rowJ * NC + m + 16];
    }
    __syncthreads();   // single preamble barrier

    float ct0 = sCT2[m], ct1 = sCT2[m + 16];
    #pragma unroll
    for (int gg = 0; gg < 4; ++gg) { cri[gg][0] += ct0; cri[gg][1] += ct1; }
    #pragma unroll
    for (int r = 0; r < 4; ++r) { crj[r][0] += ct0; crj[r][1] += ct1; }

    bf16x8 bq0 = *(const bf16x8*)&sBQ[m][8 * quad];
    bf16x8 bq1 = *(const bf16x8*)&sBQ[m + 16][8 * quad];
    bf16x8 wp0 = *(const bf16x8*)&sWp[m][8 * quad];
    bf16x8 wp1 = *(const bf16x8*)&sWp[m + 16][8 * quad];
    bf16x8 wm0 = *(const bf16x8*)&sWm[m][8 * quad];
    bf16x8 wm1 = *(const bf16x8*)&sWm[m + 16][8 * quad];
    __bf16* Uw = &sUw[wv][0][0];
    __bf16* Vw = &sVw[wv][0][0];
    f32x4 zero = {0.f, 0.f, 0.f, 0.f};
    float acc0 = 0.f, acc1 = 0.f;

    // barrier-free main loop: per-wave U/V with wave-local LDS handoff
    #pragma unroll
    for (int gg = 0; gg < 4; ++gg) {
        int g = wv * 4 + gg;
        __builtin_amdgcn_wave_barrier();   // keep prior gg's reads before writes
        {   // layer-1: h = relu(Q + T1 + R1 [+Dg]); write packed U/V
            bf16x8 av = make_av(&sXI[g][0], &sXJ[m][0], quad);
            f32x4 q0 = MFMA(av, bq0, zero);
            f32x4 q1 = MFMA(av, bq1, zero);
            #pragma unroll
            for (int r = 0; r < 4; ++r) {
                int tj = quad * 4 + r;
                float a0 = q0[r] + rti[gg][0], b0 = q0[r] + rtj[r][0];
                float a1 = q1[r] + rti[gg][1], b1 = q1[r] + rtj[r][1];
                if (diagblk && tj == g) {
                    a0 += dgi[gg][0]; b0 = a0;
                    a1 += dgi[gg][1]; b1 = a1;
                }
                float hA0 = fmaxf(a0, 0.f), hB0 = fmaxf(b0, 0.f);
                float hA1 = fmaxf(a1, 0.f), hB1 = fmaxf(b1, 0.f);
                *(unsigned*)&Uw[tj * 40 + 2 * m] = pack2(hA0 + hB0, hA1 + hB1);
                *(unsigned*)&Vw[tj * 40 + 2 * m] = pack2(hA0 - hB0, hA1 - hB1);
            }
        }
        WAVE_LDS_SYNC();
        {   // layer-2: a1 = U.Wp + V.Wm + bcast_i, a2 = U.Wp - V.Wm + bcast_j
            bf16x8 ua = *(const bf16x8*)&Uw[m * 40 + 8 * quad];
            bf16x8 va = *(const bf16x8*)&Vw[m * 40 + 8 * quad];
            f32x4 P0 = MFMA(ua, wp0, zero);
            f32x4 M0 = MFMA(va, wm0, zero);
            f32x4 P1 = MFMA(ua, wp1, zero);
            f32x4 M1 = MFMA(va, wm1, zero);
            #pragma unroll
            for (int r = 0; r < 4; ++r) {
                int tj = quad * 4 + r;
                float a1v = P0[r] + M0[r] + cri[gg][0];
                float a2v = P0[r] - M0[r] + crj[r][0];
                float e1 = P1[r] + M1[r] + cri[gg][1];
                float e2 = P1[r] - M1[r] + crj[r][1];
                if (diagblk && tj == g) { a1v += cdi[gg][0]; e1 += cdi[gg][1]; }
                acc0 += fmaxf(a1v, 0.f); acc1 += fmaxf(e1, 0.f);
                if (mirror) { acc0 += fmaxf(a2v, 0.f); acc1 += fmaxf(e2, 0.f); }
            }
        }
    }

    acc0 += __shfl_down(acc0, 32, 64); acc0 += __shfl_down(acc0, 16, 64);
    acc1 += __shfl_down(acc1, 32, 64); acc1 += __shfl_down(acc1, 16, 64);
    if (ln < 16) { red[wv][ln] = acc0; red[wv][ln + 16] = acc1; }
    __syncthreads();
    if (t < NC)
        GP[blockIdx.x * (NB * NC) + b * NC + t]
            = red[0][t] + red[1][t] + red[2][t] + red[3][t];
}

// ---------------- k5: reduce GP (136 partials) + MLP 32->128->128->1 --------
__global__ __launch_bounds__(256) void k5_mlp(
    const float* __restrict__ GP, const float* __restrict__ D1,
    const float* __restrict__ db1, const float* __restrict__ D2,
    const float* __restrict__ db2, const float* __restrict__ D3,
    const float* __restrict__ db3, float* __restrict__ out)
{
    int b = blockIdx.x, t = threadIdx.x;
    __shared__ float sGp[8][NC], a[NC], h2s[128], r2[2];
    {
        int q = t >> 5, s = t & 31;
        float p = 0.f;
        for (int k = q; k < NBLK; k += 8) p += GP[k * (NB * NC) + b * NC + s];
        sGp[q][s] = p;
    }
    __syncthreads();
    if (t < NC) {
        float s = 0.f;
        #pragma unroll
        for (int q = 0; q < 8; ++q) s += sGp[q][t];
        a[t] = fmaxf(s, 0.f);
    }
    __syncthreads();
    if (t < 128) {
        float acc = db1[t];
        #pragma unroll
        for (int s = 0; s < NC; ++s) acc += a[s] * D1[s * 128 + t];
        h2s[t] = fmaxf(acc, 0.f);
    }
    __syncthreads();
    if (t < 128) {
        float acc2 = db2[t];
        #pragma unroll 8
        for (int u = 0; u < 128; ++u) acc2 += h2s[u] * D2[u * 128 + t];
        float h3 = fmaxf(acc2, 0.f);
        float v = h3 * D3[t];
        #pragma unroll
        for (int off = 32; off > 0; off >>= 1) v += __shfl_down(v, off, 64);
        if ((t & 63) == 0) r2[t >> 6] = v;
    }
    __syncthreads();
    if (t == 0) out[b] = r2[0] + r2[1] + db3[0];
}

extern "C" void kernel_launch(void* const* d_in, const int* in_sizes, int n_in,
                              void* d_out, int out_size, void* d_ws, size_t ws_size,
                              hipStream_t stream)
{
    const float* x   = (const float*)d_in[0];
    const float* W1  = (const float*)d_in[1];
    const float* b1  = (const float*)d_in[2];
    const float* W2  = (const float*)d_in[3];
    const float* b2  = (const float*)d_in[4];
    const float* D1  = (const float*)d_in[5];
    const float* db1 = (const float*)d_in[6];
    const float* D2  = (const float*)d_in[7];
    const float* db2 = (const float*)d_in[8];
    const float* D3  = (const float*)d_in[9];
    const float* db3 = (const float*)d_in[10];
    float* out = (float*)d_out;

    float* w = (float*)d_ws;
    float* pT1   = w; w += NB * NC;          // 256
    float* pTotP = w; w += 64 * NB * NC;     // 16384
    float* pGP   = w; w += NBLK * NB * NC;   // 34816
    float* pR1   = w; w += NB * NN * NC;     // 65536
    float* pDg1  = w; w += NB * NN * NC;
    float* pCD2  = w; w += NB * NN * NC;
    float* pCR2  = w; w += NB * NN * NC;
    __bf16* pBQt = (__bf16*)w; w += 768;     // 1536 bf16 = 32x48
    __bf16* pWpm = (__bf16*)w; w += 1280;    // 2560 bf16 = Wp[32x40] + Wm[32x40]
    float* pWt4  = w; w += 1024;             // f32 [c][s]

    hipLaunchKernelGGL(kC_rows, dim3(64, NB), dim3(256), 0, stream,
                       x, W1, b1, W2, pT1, pR1, pDg1, pTotP, pCD2, pCR2,
                       pBQt, pWpm, pWt4);
    hipLaunchKernelGGL(kD_main, dim3(NBLK, NB), dim3(256), 0, stream,
                       x, pBQt, pWpm, pWt4, b2, pT1, pR1, pDg1, pCD2, pCR2,
                       pTotP, pGP);
    hipLaunchKernelGGL(k5_mlp, dim3(NB), dim3(256), 0, stream,
                       pGP, D1, db1, D2, db2, D3, db3, out);
}